// Round 3
// baseline (372.864 us; speedup 1.0000x reference)
//
#include <hip/hip_runtime.h>
#include <hip/hip_bf16.h>

#define B_ 4
#define S_ 4096
#define D_ 128

typedef __attribute__((ext_vector_type(8))) short bf16x8;   // 8 bf16 in 4 VGPRs
typedef __attribute__((ext_vector_type(4))) float f32x4;

static __device__ __forceinline__ unsigned short f2bf(float f) {
    unsigned int u = __float_as_uint(f);
    unsigned int r = (u + 0x7FFFu + ((u >> 16) & 1u)) >> 16;
    return (unsigned short)r;
}
static __device__ __forceinline__ float bf2f(unsigned short u) {
    return __uint_as_float(((unsigned int)u) << 16);
}

// 16-lane (DPP row) butterfly reductions — pure VALU, no DS pipe.
template<int CTRL>
static __device__ __forceinline__ float dppf(float x) {
    return __uint_as_float((unsigned)__builtin_amdgcn_update_dpp(
        0, (int)__float_as_uint(x), CTRL, 0xF, 0xF, true));
}
static __device__ __forceinline__ float red16_max(float x) {
    x = fmaxf(x, dppf<0xB1>(x));    // quad_perm xor1
    x = fmaxf(x, dppf<0x4E>(x));    // quad_perm xor2
    x = fmaxf(x, dppf<0x141>(x));   // row_half_mirror (xor4 after 1,2)
    x = fmaxf(x, dppf<0x140>(x));   // row_mirror      (xor8 after 1,2,4)
    return x;
}
static __device__ __forceinline__ float red16_sum(float x) {
    x += dppf<0xB1>(x);
    x += dppf<0x4E>(x);
    x += dppf<0x141>(x);
    x += dppf<0x140>(x);
    return x;
}

// ---------------------------------------------------------------------------
// Kernel A: QKV projection.  X[16384][128] f32, W[128][128] f32 each.
// Writes Qw (pre-scaled by 1/sqrt(d)), Kw row-major bf16 [16384][128];
// Vt transposed bf16 [B][128][4096].  grid = 256 x 256 thr; 64 rows/block.
// ---------------------------------------------------------------------------
__global__ __launch_bounds__(256) void qkv_proj(
    const float* __restrict__ X,
    const float* __restrict__ Wq, const float* __restrict__ Wk,
    const float* __restrict__ Wv,
    unsigned short* __restrict__ Qw, unsigned short* __restrict__ Kw,
    unsigned short* __restrict__ Vt)
{
    __shared__ alignas(16) unsigned short Xs[64][136];
    __shared__ alignas(16) unsigned short Wt[128][136];

    const int tid  = threadIdx.x;
    const int wave = tid >> 6, lane = tid & 63;
    const int lrow = lane & 15, lk = lane >> 4;
    const long r0  = (long)blockIdx.x * 64;

    for (int i = tid; i < 2048; i += 256) {
        const int s = i >> 5, c4 = (i & 31) * 4;
        const float4 v = *(const float4*)(X + (r0 + s) * D_ + c4);
        Xs[s][c4 + 0] = f2bf(v.x); Xs[s][c4 + 1] = f2bf(v.y);
        Xs[s][c4 + 2] = f2bf(v.z); Xs[s][c4 + 3] = f2bf(v.w);
    }
    __syncthreads();

    bf16x8 af[4];
#pragma unroll
    for (int kc = 0; kc < 4; ++kc)
        af[kc] = *(const bf16x8*)&Xs[wave * 16 + lrow][kc * 32 + lk * 8];

    float vacc[8][4];

#pragma unroll
    for (int w = 0; w < 3; ++w) {
        const float* W = (w == 0) ? Wq : (w == 1) ? Wk : Wv;
        for (int i = tid; i < 16384; i += 256) {
            const int rr = i >> 7, cc = i & 127;
            Wt[cc][rr] = f2bf(W[i]);
        }
        __syncthreads();

        const float osc = (w == 0) ? 0.08838834764831845f : 1.0f;  // 1/sqrt(128) folded into Q
#pragma unroll
        for (int nsub = 0; nsub < 8; ++nsub) {
            f32x4 acc = {0.f, 0.f, 0.f, 0.f};
#pragma unroll
            for (int kc = 0; kc < 4; ++kc) {
                const bf16x8 bf = *(const bf16x8*)&Wt[nsub * 16 + lrow][kc * 32 + lk * 8];
                acc = __builtin_amdgcn_mfma_f32_16x16x32_bf16(af[kc], bf, acc, 0, 0, 0);
            }
            if (w < 2) {
                unsigned short* dst = (w == 0) ? Qw : Kw;
#pragma unroll
                for (int r = 0; r < 4; ++r) {
                    const long row = r0 + wave * 16 + lk * 4 + r;
                    dst[row * D_ + nsub * 16 + lrow] = f2bf(acc[r] * osc);
                }
            } else {
#pragma unroll
                for (int r = 0; r < 4; ++r) vacc[nsub][r] = acc[r];
            }
        }
        __syncthreads();
    }

    unsigned short (*Vs)[136] = Wt;
#pragma unroll
    for (int nsub = 0; nsub < 8; ++nsub)
#pragma unroll
        for (int r = 0; r < 4; ++r)
            Vs[wave * 16 + lk * 4 + r][nsub * 16 + lrow] = f2bf(vacc[nsub][r]);
    __syncthreads();

    const int batch = (int)(r0 >> 12);
    const int sbase = (int)(r0 & 4095);
    const int dd = tid >> 1, sh = (tid & 1) * 32;
    unsigned short* vdst = Vt + (size_t)batch * D_ * S_ + (size_t)dd * S_ + sbase + sh;
    for (int j = 0; j < 32; ++j) vdst[j] = Vs[sh + j][dd];
}

// ---------------------------------------------------------------------------
// Kernel B: flash attention, 8-way in-block KV-split.
// grid = (S/16, B) = 1024 blocks, 512 threads = 8 waves (4 blocks/CU,
// 8 waves/SIMD at VGPR<=64).  Each wave: the block's 16 q-rows x 512 keys
// (kgroup = wave).  Partials merged through LDS by wave 0.
// ---------------------------------------------------------------------------
__global__ __launch_bounds__(512, 8) void attn_fwd(
    const unsigned short* __restrict__ Qw, const unsigned short* __restrict__ Kw,
    const unsigned short* __restrict__ Vt, float* __restrict__ out)
{
    // in-loop: per-wave P tiles (8 x 1152 shorts); post-loop: 7 partial slots
    // (2560 shorts each) aliased on top.
    __shared__ alignas(16) unsigned short ShBuf[17920];
    __shared__ float Stats[7][16][2];

    const int tid    = threadIdx.x;
    const int wave   = tid >> 6, lane = tid & 63;
    const int lrow   = lane & 15, lk = lane >> 4;
    const int kgroup = wave;
    const int b  = blockIdx.y;
    const int q0 = blockIdx.x * 16;

    const unsigned short* Qb = Qw + (size_t)b * S_ * D_;
    const unsigned short* Kb = Kw + (size_t)b * S_ * D_;
    const unsigned short* Vb = Vt + (size_t)b * D_ * S_;

    unsigned short* Pl = ShBuf + wave * 1152;   // 16 rows x 72 shorts

    bf16x8 qf[4];
#pragma unroll
    for (int kc = 0; kc < 4; ++kc)
        qf[kc] = *(const bf16x8*)&Qb[(size_t)(q0 + lrow) * D_ + kc * 32 + lk * 8];

    f32x4 oacc[8];
#pragma unroll
    for (int i = 0; i < 8; ++i) oacc[i] = (f32x4){0.f, 0.f, 0.f, 0.f};
    float m[4], l[4];
#pragma unroll
    for (int r = 0; r < 4; ++r) { m[r] = -1e30f; l[r] = 0.f; }

    const int kv_base = kgroup * 512;

    for (int t = 0; t < 8; ++t) {
        const int kv0 = kv_base + t * 64;
        // ---- S = Q @ K^T (scale pre-folded into Q) ----
        f32x4 sacc[4];
#pragma unroll
        for (int n = 0; n < 4; ++n) sacc[n] = (f32x4){0.f, 0.f, 0.f, 0.f};
#pragma unroll
        for (int n = 0; n < 4; ++n) {
#pragma unroll
            for (int kc = 0; kc < 4; ++kc) {
                const bf16x8 kf = *(const bf16x8*)
                    &Kb[(size_t)(kv0 + n * 16 + lrow) * D_ + kc * 32 + lk * 8];
                sacc[n] = __builtin_amdgcn_mfma_f32_16x16x32_bf16(qf[kc], kf, sacc[n], 0, 0, 0);
            }
        }
        // ---- online softmax; reductions via DPP (VALU), defer-max skip ----
        float tmax[4];
#pragma unroll
        for (int r = 0; r < 4; ++r)
            tmax[r] = red16_max(fmaxf(fmaxf(sacc[0][r], sacc[1][r]),
                                      fmaxf(sacc[2][r], sacc[3][r])));
        int need = 0;
#pragma unroll
        for (int r = 0; r < 4; ++r) need |= (tmax[r] > m[r] + 8.f);
        if (__any(need)) {
#pragma unroll
            for (int r = 0; r < 4; ++r) {
                const float mn = fmaxf(m[r], tmax[r]);
                const float corr = __expf(m[r] - mn);
                m[r] = mn;
                l[r] *= corr;
#pragma unroll
                for (int o = 0; o < 8; ++o) oacc[o][r] *= corr;
            }
        }
        float tsum[4] = {0.f, 0.f, 0.f, 0.f};
#pragma unroll
        for (int n = 0; n < 4; ++n)
#pragma unroll
            for (int r = 0; r < 4; ++r) {
                const float p = __expf(sacc[n][r] - m[r]);
                tsum[r] += p;
                Pl[(lk * 4 + r) * 72 + n * 16 + lrow] = f2bf(p);
            }
#pragma unroll
        for (int r = 0; r < 4; ++r) l[r] += red16_sum(tsum[r]);

        // P writes must land before A-fragment reads (same wave, DS queue)
        asm volatile("s_waitcnt lgkmcnt(0)" ::: "memory");

        // ---- O += P @ V ----
#pragma unroll
        for (int kc2 = 0; kc2 < 2; ++kc2) {
            const bf16x8 pf = *(const bf16x8*)&Pl[lrow * 72 + kc2 * 32 + lk * 8];
#pragma unroll
            for (int o = 0; o < 8; ++o) {
                const bf16x8 vf = *(const bf16x8*)
                    &Vb[(size_t)(o * 16 + lrow) * S_ + kv0 + kc2 * 32 + lk * 8];
                oacc[o] = __builtin_amdgcn_mfma_f32_16x16x32_bf16(pf, vf, oacc[o], 0, 0, 0);
            }
        }
    }

    // ---- cross-wave combine over the 8 KV groups ----
    __syncthreads();

    if (kgroup > 0) {
        const int s = wave - 1;
        unsigned short* Pp = ShBuf + s * 2560 + lane * 40;
#pragma unroll
        for (int c = 0; c < 4; ++c) {
            bf16x8 v;
#pragma unroll
            for (int i = 0; i < 8; ++i) {
                const int idx = c * 8 + i;
                v[i] = (short)f2bf(oacc[idx >> 2][idx & 3]);
            }
            *(bf16x8*)(Pp + c * 8) = v;
        }
        if (lrow == 0) {
#pragma unroll
            for (int r = 0; r < 4; ++r) {
                Stats[s][lk * 4 + r][0] = m[r];
                Stats[s][lk * 4 + r][1] = l[r];
            }
        }
    }
    __syncthreads();

    if (kgroup == 0) {
#pragma unroll
        for (int j = 1; j < 8; ++j) {
            const int s = j - 1;
            const unsigned short* Pp = ShBuf + s * 2560 + lane * 40;
            bf16x8 ch[4];
#pragma unroll
            for (int c = 0; c < 4; ++c) ch[c] = *(const bf16x8*)(Pp + c * 8);
            float mj[4], lj[4], a[4], bb[4];
#pragma unroll
            for (int r = 0; r < 4; ++r) {
                mj[r] = Stats[s][lk * 4 + r][0];
                lj[r] = Stats[s][lk * 4 + r][1];
                const float mn = fmaxf(m[r], mj[r]);
                a[r]  = __expf(m[r]  - mn);
                bb[r] = __expf(mj[r] - mn);
                l[r] = l[r] * a[r] + lj[r] * bb[r];
                m[r] = mn;
            }
#pragma unroll
            for (int c = 0; c < 4; ++c)
#pragma unroll
                for (int i = 0; i < 8; ++i) {
                    const int idx = c * 8 + i;
                    const int o = idx >> 2, r = idx & 3;
                    oacc[o][r] = oacc[o][r] * a[r] + bf2f((unsigned short)ch[c][i]) * bb[r];
                }
        }
        float inv[4];
#pragma unroll
        for (int r = 0; r < 4; ++r) inv[r] = 1.f / l[r];
        float* ob = out + ((size_t)b * S_ + q0) * D_;
#pragma unroll
        for (int o = 0; o < 8; ++o)
#pragma unroll
            for (int r = 0; r < 4; ++r)
                ob[(size_t)(lk * 4 + r) * D_ + o * 16 + lrow] = oacc[o][r] * inv[r];
    }
}

// ---------------------------------------------------------------------------
extern "C" void kernel_launch(void* const* d_in, const int* in_sizes, int n_in,
                              void* d_out, int out_size, void* d_ws, size_t ws_size,
                              hipStream_t stream) {
    const float* X  = (const float*)d_in[0];
    const float* Wq = (const float*)d_in[1];
    const float* Wk = (const float*)d_in[2];
    const float* Wv = (const float*)d_in[3];
    float* out = (float*)d_out;

    unsigned short* Qw = (unsigned short*)d_ws;
    unsigned short* Kw = Qw + (size_t)B_ * S_ * D_;
    unsigned short* Vt = Kw + (size_t)B_ * S_ * D_;

    qkv_proj<<<dim3(B_ * S_ / 64), 256, 0, stream>>>(X, Wq, Wk, Wv, Qw, Kw, Vt);
    attn_fwd<<<dim3(S_ / 16, B_), 512, 0, stream>>>(Qw, Kw, Vt, out);
}

// Round 4
// 124.959 us; speedup vs baseline: 2.9839x; 2.9839x over previous
//
#include <hip/hip_runtime.h>
#include <hip/hip_bf16.h>

#define B_ 4
#define S_ 4096
#define D_ 128
#define KVBLK 32
#define NT 64           // tiles per kv-group: 2048/32

typedef __attribute__((ext_vector_type(8))) short bf16x8;   // 8 bf16 in 4 VGPRs
typedef __attribute__((ext_vector_type(4))) float f32x4;

static __device__ __forceinline__ unsigned short f2bf(float f) {
    unsigned int u = __float_as_uint(f);
    unsigned int r = (u + 0x7FFFu + ((u >> 16) & 1u)) >> 16;
    return (unsigned short)r;
}
static __device__ __forceinline__ float bf2f(unsigned short u) {
    return __uint_as_float(((unsigned int)u) << 16);
}

// 16-lane (DPP row) butterfly reductions — pure VALU, no DS pipe.
template<int CTRL>
static __device__ __forceinline__ float dppf(float x) {
    return __uint_as_float((unsigned)__builtin_amdgcn_update_dpp(
        0, (int)__float_as_uint(x), CTRL, 0xF, 0xF, true));
}
static __device__ __forceinline__ float red16_max(float x) {
    x = fmaxf(x, dppf<0xB1>(x));
    x = fmaxf(x, dppf<0x4E>(x));
    x = fmaxf(x, dppf<0x141>(x));
    x = fmaxf(x, dppf<0x140>(x));
    return x;
}
static __device__ __forceinline__ float red16_sum(float x) {
    x += dppf<0xB1>(x);
    x += dppf<0x4E>(x);
    x += dppf<0x141>(x);
    x += dppf<0x140>(x);
    return x;
}

// async global -> LDS, 16 B per lane; LDS dest = uniform base + lane*16.
#define GLOAD_LDS16(gsrc, ldst)                                                   \
    __builtin_amdgcn_global_load_lds(                                             \
        (const __attribute__((address_space(1))) unsigned int*)(gsrc),            \
        (__attribute__((address_space(3))) unsigned int*)(ldst), 16, 0, 0)

// ---------------------------------------------------------------------------
// Kernel A: QKV projection (unchanged; Q pre-scaled by 1/sqrt(d)).
// ---------------------------------------------------------------------------
__global__ __launch_bounds__(256) void qkv_proj(
    const float* __restrict__ X,
    const float* __restrict__ Wq, const float* __restrict__ Wk,
    const float* __restrict__ Wv,
    unsigned short* __restrict__ Qw, unsigned short* __restrict__ Kw,
    unsigned short* __restrict__ Vt)
{
    __shared__ alignas(16) unsigned short Xs[64][136];
    __shared__ alignas(16) unsigned short Wt[128][136];

    const int tid  = threadIdx.x;
    const int wave = tid >> 6, lane = tid & 63;
    const int lrow = lane & 15, lk = lane >> 4;
    const long r0  = (long)blockIdx.x * 64;

    for (int i = tid; i < 2048; i += 256) {
        const int s = i >> 5, c4 = (i & 31) * 4;
        const float4 v = *(const float4*)(X + (r0 + s) * D_ + c4);
        Xs[s][c4 + 0] = f2bf(v.x); Xs[s][c4 + 1] = f2bf(v.y);
        Xs[s][c4 + 2] = f2bf(v.z); Xs[s][c4 + 3] = f2bf(v.w);
    }
    __syncthreads();

    bf16x8 af[4];
#pragma unroll
    for (int kc = 0; kc < 4; ++kc)
        af[kc] = *(const bf16x8*)&Xs[wave * 16 + lrow][kc * 32 + lk * 8];

    float vacc[8][4];

#pragma unroll
    for (int w = 0; w < 3; ++w) {
        const float* W = (w == 0) ? Wq : (w == 1) ? Wk : Wv;
        for (int i = tid; i < 16384; i += 256) {
            const int rr = i >> 7, cc = i & 127;
            Wt[cc][rr] = f2bf(W[i]);
        }
        __syncthreads();

        const float osc = (w == 0) ? 0.08838834764831845f : 1.0f;
#pragma unroll
        for (int nsub = 0; nsub < 8; ++nsub) {
            f32x4 acc = {0.f, 0.f, 0.f, 0.f};
#pragma unroll
            for (int kc = 0; kc < 4; ++kc) {
                const bf16x8 bf = *(const bf16x8*)&Wt[nsub * 16 + lrow][kc * 32 + lk * 8];
                acc = __builtin_amdgcn_mfma_f32_16x16x32_bf16(af[kc], bf, acc, 0, 0, 0);
            }
            if (w < 2) {
                unsigned short* dst = (w == 0) ? Qw : Kw;
#pragma unroll
                for (int r = 0; r < 4; ++r) {
                    const long row = r0 + wave * 16 + lk * 4 + r;
                    dst[row * D_ + nsub * 16 + lrow] = f2bf(acc[r] * osc);
                }
            } else {
#pragma unroll
                for (int r = 0; r < 4; ++r) vacc[nsub][r] = acc[r];
            }
        }
        __syncthreads();
    }

    unsigned short (*Vs)[136] = Wt;
#pragma unroll
    for (int nsub = 0; nsub < 8; ++nsub)
#pragma unroll
        for (int r = 0; r < 4; ++r)
            Vs[wave * 16 + lk * 4 + r][nsub * 16 + lrow] = f2bf(vacc[nsub][r]);
    __syncthreads();

    const int batch = (int)(r0 >> 12);
    const int sbase = (int)(r0 & 4095);
    const int dd = tid >> 1, sh = (tid & 1) * 32;
    unsigned short* vdst = Vt + (size_t)batch * D_ * S_ + (size_t)dd * S_ + sbase + sh;
    for (int j = 0; j < 32; ++j) vdst[j] = Vs[sh + j][dd];
}

// ---------------------------------------------------------------------------
// Kernel B: flash attention with async LDS staging.
// grid = (64, 4), 512 threads = 8 waves = 4 q-waves x 2 kv-groups.
// Per kv-group: K tiles double-buffered (XOR-swizzled), V single-buffered
// (staged at tile top, covered by QK^T+softmax), both via global_load_lds.
// LDS byte map: K[g][buf] 4x8KB = 32768 | V[g] 2x8KB = 16384 | P 8x1280
//   = 59392 B total; merge slots alias the K region after the loop.
// ---------------------------------------------------------------------------
__global__ __launch_bounds__(512, 2) void attn_fwd(
    const unsigned short* __restrict__ Qw, const unsigned short* __restrict__ Kw,
    const unsigned short* __restrict__ Vt, float* __restrict__ out)
{
    __shared__ alignas(16) char SH[59392];
    __shared__ float Stats[4][16][2];

    const int tid    = threadIdx.x;
    const int wave   = tid >> 6, lane = tid & 63;
    const int lrow   = lane & 15, lk = lane >> 4;
    const int qwave  = wave & 3, kvgroup = wave >> 2;
    const int b  = blockIdx.y;
    const int q0 = blockIdx.x * 64 + qwave * 16;

    const unsigned short* Qb = Qw + (size_t)b * S_ * D_;
    const unsigned short* Kb = Kw + (size_t)b * S_ * D_;
    const unsigned short* Vb = Vt + (size_t)b * D_ * S_;

    // LDS region bases (bytes)
    const int KB0 = kvgroup * 16384;            // + buf*8192
    const int VBg = 32768 + kvgroup * 8192;
    const int PBw = 49152 + wave * 1280;        // 16 rows x 40 shorts
    unsigned short* Pl = (unsigned short*)(SH + PBw);

    // Q fragments, held in registers
    bf16x8 qf[4];
#pragma unroll
    for (int kc = 0; kc < 4; ++kc)
        qf[kc] = *(const bf16x8*)&Qb[(size_t)(q0 + lrow) * D_ + kc * 32 + lk * 8];

    f32x4 oacc[8];
#pragma unroll
    for (int i = 0; i < 8; ++i) oacc[i] = (f32x4){0.f, 0.f, 0.f, 0.f};
    float m[4], l[4];
#pragma unroll
    for (int r = 0; r < 4; ++r) { m[r] = -1e30f; l[r] = 0.f; }

    const int kv_base = kvgroup * 2048;

    // ---- staging helpers (per wave: 2 calls K, 2 calls V per tile) ----
    // K tile [32 rows][256B]: line L -> row=L>>4, chunk c=L&15; content at
    // (row,c) is logical chunk c^(row&15)  => source pre-swizzled.
    // V tile [128 d-rows][64B]: line L -> row=L>>2, c=L&3; swz c^(row&3).
#define STAGE_K(bufb, kvt)                                                        \
    {                                                                             \
        const int kv0s = kv_base + (kvt) * KVBLK;                                 \
        _Pragma("unroll")                                                         \
        for (int j = 0; j < 2; ++j) {                                             \
            const int L = qwave * 128 + j * 64 + lane;                            \
            const int row = L >> 4, c = L & 15;                                   \
            const unsigned short* gs =                                            \
                Kb + ((size_t)(kv0s + row) << 7) + ((c ^ (row & 15)) << 3);       \
            GLOAD_LDS16(gs, SH + KB0 + (bufb) * 8192 + (qwave * 128 + j * 64) * 16); \
        }                                                                         \
    }
#define STAGE_V(kvt)                                                              \
    {                                                                             \
        const int kv0s = kv_base + (kvt) * KVBLK;                                 \
        _Pragma("unroll")                                                         \
        for (int j = 0; j < 2; ++j) {                                             \
            const int L = qwave * 128 + j * 64 + lane;                            \
            const int row = L >> 2, c = L & 3;                                    \
            const unsigned short* gs =                                            \
                Vb + (size_t)row * S_ + kv0s + ((c ^ (row & 3)) << 3);            \
            GLOAD_LDS16(gs, SH + VBg + (qwave * 128 + j * 64) * 16);              \
        }                                                                         \
    }

    STAGE_K(0, 0);    // prologue

    for (int t = 0; t < NT; ++t) {
        __syncthreads();            // K(t) landed (auto vm-drain) + buffers free
        STAGE_V(t);
        if (t + 1 < NT) STAGE_K((t + 1) & 1, t + 1);

        // ---- S = Q @ K^T from swizzled LDS K tile ----
        const char* Kbuf = SH + KB0 + (t & 1) * 8192;
        f32x4 sacc[2];
#pragma unroll
        for (int n = 0; n < 2; ++n) sacc[n] = (f32x4){0.f, 0.f, 0.f, 0.f};
#pragma unroll
        for (int n = 0; n < 2; ++n) {
            const int row = n * 16 + lrow;
#pragma unroll
            for (int kc = 0; kc < 4; ++kc) {
                const bf16x8 kf = *(const bf16x8*)
                    (Kbuf + row * 256 + (((kc * 4 + lk) ^ lrow) << 4));
                sacc[n] = __builtin_amdgcn_mfma_f32_16x16x32_bf16(qf[kc], kf, sacc[n], 0, 0, 0);
            }
        }

        // ---- online softmax (DPP reductions, defer-max) ----
        float tmax[4];
#pragma unroll
        for (int r = 0; r < 4; ++r)
            tmax[r] = red16_max(fmaxf(sacc[0][r], sacc[1][r]));
        int need = 0;
#pragma unroll
        for (int r = 0; r < 4; ++r) need |= (tmax[r] > m[r] + 8.f);
        if (__any(need)) {
#pragma unroll
            for (int r = 0; r < 4; ++r) {
                const float mn = fmaxf(m[r], tmax[r]);
                const float corr = __expf(m[r] - mn);
                m[r] = mn;
                l[r] *= corr;
#pragma unroll
                for (int o = 0; o < 8; ++o) oacc[o][r] *= corr;
            }
        }
        float tsum[4] = {0.f, 0.f, 0.f, 0.f};
#pragma unroll
        for (int n = 0; n < 2; ++n)
#pragma unroll
            for (int r = 0; r < 4; ++r) {
                const float p = __expf(sacc[n][r] - m[r]);
                tsum[r] += p;
                Pl[(lk * 4 + r) * 40 + n * 16 + lrow] = f2bf(p);
            }
#pragma unroll
        for (int r = 0; r < 4; ++r) l[r] += red16_sum(tsum[r]);

        // P writes visible + staged V(t) (and K(t+1)) landed
        asm volatile("s_waitcnt vmcnt(0) lgkmcnt(0)" ::: "memory");

        // ---- O += P @ V from swizzled LDS V tile ----
        const bf16x8 pf = *(const bf16x8*)&Pl[lrow * 40 + lk * 8];
#pragma unroll
        for (int o = 0; o < 8; ++o) {
            const int row = o * 16 + lrow;
            const bf16x8 vf = *(const bf16x8*)
                (SH + VBg + row * 64 + ((lk ^ (lrow & 3)) << 4));
            oacc[o] = __builtin_amdgcn_mfma_f32_16x16x32_bf16(pf, vf, oacc[o], 0, 0, 0);
        }
    }

    // ---- cross-wave combine over the 2 kv-groups (merge aliases K region) ----
    __syncthreads();

    if (kvgroup == 1) {
        unsigned short* Pp = (unsigned short*)(SH + qwave * 5120) + lane * 40;
#pragma unroll
        for (int c = 0; c < 4; ++c) {
            bf16x8 v;
#pragma unroll
            for (int i = 0; i < 8; ++i) {
                const int idx = c * 8 + i;
                v[i] = (short)f2bf(oacc[idx >> 2][idx & 3]);
            }
            *(bf16x8*)(Pp + c * 8) = v;
        }
        if (lrow == 0) {
#pragma unroll
            for (int r = 0; r < 4; ++r) {
                Stats[qwave][lk * 4 + r][0] = m[r];
                Stats[qwave][lk * 4 + r][1] = l[r];
            }
        }
    }
    __syncthreads();

    if (kvgroup == 0) {
        const unsigned short* Pp = (const unsigned short*)(SH + qwave * 5120) + lane * 40;
        bf16x8 ch[4];
#pragma unroll
        for (int c = 0; c < 4; ++c) ch[c] = *(const bf16x8*)(Pp + c * 8);
        float a[4], bb[4];
#pragma unroll
        for (int r = 0; r < 4; ++r) {
            const float mj = Stats[qwave][lk * 4 + r][0];
            const float lj = Stats[qwave][lk * 4 + r][1];
            const float mn = fmaxf(m[r], mj);
            a[r]  = __expf(m[r] - mn);
            bb[r] = __expf(mj   - mn);
            l[r] = l[r] * a[r] + lj * bb[r];
        }
#pragma unroll
        for (int c = 0; c < 4; ++c)
#pragma unroll
            for (int i = 0; i < 8; ++i) {
                const int idx = c * 8 + i;
                const int o = idx >> 2, r = idx & 3;
                oacc[o][r] = oacc[o][r] * a[r] + bf2f((unsigned short)ch[c][i]) * bb[r];
            }
        float inv[4];
#pragma unroll
        for (int r = 0; r < 4; ++r) inv[r] = 1.f / l[r];
        float* ob = out + ((size_t)b * S_ + q0) * D_;
#pragma unroll
        for (int o = 0; o < 8; ++o)
#pragma unroll
            for (int r = 0; r < 4; ++r)
                ob[(size_t)(lk * 4 + r) * D_ + o * 16 + lrow] = oacc[o][r] * inv[r];
    }
}

// ---------------------------------------------------------------------------
extern "C" void kernel_launch(void* const* d_in, const int* in_sizes, int n_in,
                              void* d_out, int out_size, void* d_ws, size_t ws_size,
                              hipStream_t stream) {
    const float* X  = (const float*)d_in[0];
    const float* Wq = (const float*)d_in[1];
    const float* Wk = (const float*)d_in[2];
    const float* Wv = (const float*)d_in[3];
    float* out = (float*)d_out;

    unsigned short* Qw = (unsigned short*)d_ws;
    unsigned short* Kw = Qw + (size_t)B_ * S_ * D_;
    unsigned short* Vt = Kw + (size_t)B_ * S_ * D_;

    qkv_proj<<<dim3(B_ * S_ / 64), 256, 0, stream>>>(X, Wq, Wk, Wv, Qw, Kw, Vt);
    attn_fwd<<<dim3(S_ / 64, B_), 512, 0, stream>>>(Qw, Kw, Vt, out);
}